// Round 1
// baseline (907.341 us; speedup 1.0000x reference)
//
#include <hip/hip_runtime.h>
#include <math.h>

#define NGRID 8192
#define NB 32
#define NCH 64

__device__ __forceinline__ float gelu_f(float x){
    return 0.5f * x * (1.0f + erff(x * 0.70710678118654752f));
}

// Dfwd[n][j], j<64: cos(2*pi*j*n/N), j>=64: sin(2*pi*(j-64)*n/N)
__global__ void k_basis_fwd(float* __restrict__ D){
    int t = blockIdx.x * 256 + threadIdx.x;   // 8192*128
    int n = t >> 7, j = t & 127, k = j & 63;
    int r = (k * n) & (NGRID - 1);
    float s, c;
    sincosf((float)r * 7.6699039394282061e-4f, &s, &c);
    D[t] = (j < 64) ? c : s;
}

// Dinv[j][n], j<64: cos row k=j ; j>=64: sin row k=j-64
__global__ void k_basis_inv(float* __restrict__ D){
    int t = blockIdx.x * 256 + threadIdx.x;   // 128*8192
    int j = t >> 13, n = t & (NGRID - 1), k = j & 63;
    int r = (k * n) & (NGRID - 1);
    float s, c;
    sincosf((float)r * 7.6699039394282061e-4f, &s, &c);
    D[t] = (j < 64) ? c : s;
}

// h[b][c][n] = x[b]·lift_w[c,0:5] + grid[n]*lift_w[c,5] + lift_b[c]
__global__ void k_lift(const float* __restrict__ x, const float* __restrict__ lw,
                       const float* __restrict__ lb, float* __restrict__ h){
    const int bc = blockIdx.x;             // b*64 + c
    const int b = bc >> 6, c = bc & 63;
    float A = lb[c];
    #pragma unroll
    for(int d = 0; d < 5; d++) A = fmaf(x[b*5 + d], lw[c*6 + d], A);
    const float v = lw[c*6 + 5];
    float* hp = h + (size_t)bc * NGRID;
    for(int n = threadIdx.x; n < NGRID; n += 256)
        hp[n] = fmaf((float)n * (1.0f/8191.0f), v, A);
}

// DFT GEMM: part[sp][m][j] = sum_{k in chunk} h[m][k] * Dfwd[k][j]
// grid (32 m-tiles of 64, splits), block 256, micro 4x8
__global__ __launch_bounds__(256) void k_dft(const float* __restrict__ h,
                                             const float* __restrict__ Dfwd,
                                             float* __restrict__ part,
                                             int chunk){
    const int m0 = blockIdx.x * 64;
    const int sp = blockIdx.y;
    const int kbase = sp * chunk;
    __shared__ float AsT[32][68];
    __shared__ float Bs[32][128];
    const int tid = threadIdx.x;
    const int tr = tid >> 4;   // 0..15 -> rows tr*4+u
    const int tc = tid & 15;   // cols tc*8+v
    float acc[4][8];
    #pragma unroll
    for(int u=0;u<4;u++)
        #pragma unroll
        for(int v=0;v<8;v++) acc[u][v] = 0.f;

    for(int k0 = kbase; k0 < kbase + chunk; k0 += 32){
        {
            const int kk = tid & 31, r0 = tid >> 5;
            #pragma unroll
            for(int p=0;p<8;p++){
                const int row = r0 + p*8;
                AsT[kk][row] = h[(size_t)(m0+row)*NGRID + k0 + kk];
            }
        }
        {
            const int j = tid & 127, kb = tid >> 7;
            #pragma unroll
            for(int q=0;q<16;q++){
                const int kk = kb + q*2;
                Bs[kk][j] = Dfwd[(size_t)(k0+kk)*128 + j];
            }
        }
        __syncthreads();
        #pragma unroll
        for(int kk=0;kk<32;kk++){
            float a[4], bv[8];
            #pragma unroll
            for(int u=0;u<4;u++) a[u] = AsT[kk][tr*4+u];
            #pragma unroll
            for(int v=0;v<8;v++) bv[v] = Bs[kk][tc*8+v];
            #pragma unroll
            for(int u=0;u<4;u++)
                #pragma unroll
                for(int v=0;v<8;v++)
                    acc[u][v] = fmaf(a[u], bv[v], acc[u][v]);
        }
        __syncthreads();
    }
    float* P = part + (size_t)sp * (2048*128);
    #pragma unroll
    for(int u=0;u<4;u++){
        const int row = m0 + tr*4 + u;
        #pragma unroll
        for(int v=0;v<8;v++)
            P[(size_t)row*128 + tc*8 + v] = acc[u][v];
    }
}

__global__ void k_reduce(const float* __restrict__ part, float* __restrict__ Hf, int splits){
    const int t = blockIdx.x*256 + threadIdx.x;   // 262144
    float s = 0.f;
    for(int i=0;i<splits;i++) s += part[(size_t)i*(2048*128) + t];
    Hf[t] = s;
}

// mode mix + pack U[b][o][0:64]=cos coefs, [64:128]=sin coefs, [128:192]=wc row
__global__ __launch_bounds__(64) void k_mix(const float* __restrict__ Hf,
        const float* __restrict__ spW, const float* __restrict__ wcw,
        float* __restrict__ U, int l){
    const int bo = blockIdx.x;          // b*64+o
    const int b = bo >> 6, o = bo & 63;
    const int k = threadIdx.x;          // 0..63
    const float* Hb = Hf + (size_t)b*64*128;
    const float* W = spW + (size_t)l*64*64*64*2;
    float ar = 0.f, ai = 0.f;
    for(int i=0;i<64;i++){
        const float hr = Hb[i*128 + k];        // real part
        const float hs = Hb[i*128 + 64 + k];   // +sin sum; imag = -hs
        const float* wp = W + (((size_t)i*64 + o)*64 + k)*2;
        const float wr = wp[0], wi = wp[1];
        ar = fmaf(hr, wr, fmaf(hs, wi, ar));   // Re(H*W) = hr*wr - (-hs)*wi
        ai = fmaf(hr, wi, fmaf(-hs, wr, ai));  // Im(H*W) = hr*wi + (-hs)*wr
    }
    const float ck = (k==0) ? (1.0f/8192.0f) : (2.0f/8192.0f);
    float* Ub = U + (size_t)bo * 192;
    Ub[k]       = ck * ar;
    Ub[64 + k]  = -ck * ai;
    Ub[128 + k] = wcw[(size_t)l*4096 + o*64 + k];
}

// fused inverse-DFT + 1x1 conv + bias + gelu; in-place update of h
// grid (64 n-tiles of 128, 32 b), block 256, micro 4x8
__global__ __launch_bounds__(256) void k_apply(const float* __restrict__ U,
                                               const float* __restrict__ Dinv,
                                               const float* __restrict__ wcb,
                                               float* __restrict__ h,
                                               int l){
    const int n0 = blockIdx.x * 128;
    const int b  = blockIdx.y;
    __shared__ float UsT[32][68];
    __shared__ float Vs[32][128];
    const int tid = threadIdx.x, tr = tid >> 4, tc = tid & 15;
    float acc[4][8];
    #pragma unroll
    for(int u=0;u<4;u++)
        #pragma unroll
        for(int v=0;v<8;v++) acc[u][v] = 0.f;
    const float* Ub = U + (size_t)b * (64*192);

    for(int k0=0;k0<192;k0+=32){
        {
            const int kk = tid & 31, r0 = tid >> 5;
            #pragma unroll
            for(int p=0;p<8;p++){
                const int o = r0 + p*8;
                UsT[kk][o] = Ub[o*192 + k0 + kk];
            }
        }
        {
            const int j = tid & 127, kb = tid >> 7;
            #pragma unroll
            for(int q=0;q<16;q++){
                const int kk = kb + q*2;
                const int kg = k0 + kk;
                const float* rp = (kg < 128) ? (Dinv + (size_t)kg*NGRID)
                                             : (h + ((size_t)b*64 + (kg-128))*NGRID);
                Vs[kk][j] = rp[n0 + j];
            }
        }
        __syncthreads();
        #pragma unroll
        for(int kk=0;kk<32;kk++){
            float a[4], bv[8];
            #pragma unroll
            for(int u=0;u<4;u++) a[u] = UsT[kk][tr*4+u];
            #pragma unroll
            for(int v=0;v<8;v++) bv[v] = Vs[kk][tc*8+v];
            #pragma unroll
            for(int u=0;u<4;u++)
                #pragma unroll
                for(int v=0;v<8;v++)
                    acc[u][v] = fmaf(a[u], bv[v], acc[u][v]);
        }
        __syncthreads();
    }
    #pragma unroll
    for(int u=0;u<4;u++){
        const int o = tr*4 + u;
        const float bias = wcb[l*64 + o];
        float* hp = h + ((size_t)b*64 + o)*NGRID + n0 + tc*8;
        #pragma unroll
        for(int v=0;v<8;v++)
            hp[v] = gelu_f(acc[u][v] + bias);
    }
}

// projection: y[b][n] = p2 · gelu(p1 @ h[:,n] + p1b) + p2b
// grid (64 n-tiles, 32 b), block 256, micro 8(j) x 8(n)
__global__ __launch_bounds__(256) void k_proj(const float* __restrict__ h,
        const float* __restrict__ p1w, const float* __restrict__ p1b,
        const float* __restrict__ p2w, const float* __restrict__ p2b,
        float* __restrict__ out){
    const int n0 = blockIdx.x * 128;
    const int b  = blockIdx.y;
    __shared__ float Hs[64][128];
    __shared__ float P1T[64][128];
    const int tid = threadIdx.x, tr = tid >> 4, tc = tid & 15;
    {
        const int j = tid & 127, cb = tid >> 7;
        #pragma unroll
        for(int q=0;q<32;q++){
            const int c = cb + q*2;
            Hs[c][j] = h[((size_t)b*64 + c)*NGRID + n0 + j];
        }
    }
    {
        #pragma unroll
        for(int q=0;q<32;q++){
            const int e = q*256 + tid;
            const int j = e & 127, c = e >> 7;
            P1T[c][j] = p1w[j*64 + c];
        }
    }
    __syncthreads();
    float acc[8][8];
    #pragma unroll
    for(int u=0;u<8;u++)
        #pragma unroll
        for(int v=0;v<8;v++) acc[u][v] = 0.f;
    for(int c=0;c<64;c++){
        float pv[8], hv[8];
        #pragma unroll
        for(int u=0;u<8;u++) pv[u] = P1T[c][tr*8+u];
        #pragma unroll
        for(int v=0;v<8;v++) hv[v] = Hs[c][tc*8+v];
        #pragma unroll
        for(int u=0;u<8;u++)
            #pragma unroll
            for(int v=0;v<8;v++)
                acc[u][v] = fmaf(pv[u], hv[v], acc[u][v]);
    }
    float pd[8];
    #pragma unroll
    for(int v=0;v<8;v++) pd[v] = 0.f;
    #pragma unroll
    for(int u=0;u<8;u++){
        const int j = tr*8 + u;
        const float bj = p1b[j], wj = p2w[j];
        #pragma unroll
        for(int v=0;v<8;v++)
            pd[v] = fmaf(wj, gelu_f(acc[u][v] + bj), pd[v]);
    }
    __syncthreads();
    float* red = &P1T[0][0];   // reuse LDS (done reading P1T)
    #pragma unroll
    for(int v=0;v<8;v++) red[tr*128 + tc*8 + v] = pd[v];
    __syncthreads();
    if(tid < 128){
        float sY = p2b[0];
        #pragma unroll
        for(int r=0;r<16;r++) sY += red[r*128 + tid];
        out[(size_t)b*NGRID + n0 + tid] = sY;
    }
}

extern "C" void kernel_launch(void* const* d_in, const int* in_sizes, int n_in,
                              void* d_out, int out_size, void* d_ws, size_t ws_size,
                              hipStream_t stream){
    const float* x   = (const float*)d_in[0];
    const float* lw  = (const float*)d_in[1];
    const float* lb  = (const float*)d_in[2];
    const float* spW = (const float*)d_in[3];
    const float* wcw = (const float*)d_in[4];
    const float* wcb = (const float*)d_in[5];
    const float* p1w = (const float*)d_in[6];
    const float* p1b = (const float*)d_in[7];
    const float* p2w = (const float*)d_in[8];
    const float* p2b = (const float*)d_in[9];
    float* out = (float*)d_out;
    float* ws  = (float*)d_ws;

    float* Dfwd = ws;                                   // 8192*128
    float* Dinv = Dfwd + (size_t)8192*128;              // 128*8192
    float* h    = Dinv + (size_t)128*8192;              // 32*64*8192
    float* Hf   = h    + (size_t)32*64*8192;            // 2048*128
    float* U    = Hf   + (size_t)2048*128;              // 32*64*192
    float* part = U    + (size_t)32*64*192;             // splits*2048*128

    const size_t fixedf = (size_t)8192*128*2 + (size_t)32*64*8192
                        + (size_t)2048*128 + (size_t)32*64*192;
    int splits = 32;
    while(splits > 1 && (fixedf + (size_t)splits*2048*128)*sizeof(float) > ws_size)
        splits >>= 1;
    const int chunk = 8192 / splits;

    k_basis_fwd<<<dim3(4096), dim3(256), 0, stream>>>(Dfwd);
    k_basis_inv<<<dim3(4096), dim3(256), 0, stream>>>(Dinv);
    k_lift<<<dim3(2048), dim3(256), 0, stream>>>(x, lw, lb, h);
    for(int l=0;l<4;l++){
        k_dft<<<dim3(32, splits), dim3(256), 0, stream>>>(h, Dfwd, part, chunk);
        k_reduce<<<dim3(1024), dim3(256), 0, stream>>>(part, Hf, splits);
        k_mix<<<dim3(2048), dim3(64), 0, stream>>>(Hf, spW, wcw, U, l);
        k_apply<<<dim3(64, 32), dim3(256), 0, stream>>>(U, Dinv, wcb, h, l);
    }
    k_proj<<<dim3(64, 32), dim3(256), 0, stream>>>(h, p1w, p1b, p2w, p2b, out);
}